// Round 13
// baseline (511.337 us; speedup 1.0000x reference)
//
#include <hip/hip_runtime.h>
#include <hip/hip_bf16.h>
#include <math.h>

typedef __bf16 bf16_t;
typedef __attribute__((ext_vector_type(8))) __bf16 bf16x8;
typedef __attribute__((ext_vector_type(4))) __bf16 bf16x4;
typedef __attribute__((ext_vector_type(4))) float f32x4;

#define T_TOK 100352      // 32 * 3136 tokens (= Bw*N = 2048*49)
#define DIMC 256
#define HEADS 8
#define HD 32
#define NTOK 49
#define SHIFT3 3
#define HH 56
#define SCALE_QK 0.17677669529663687f

__device__ __forceinline__ int xrow_of(int rr) {
    int wi = rr / 49; int t = rr - wi * 49;
    int b = wi >> 6; int w64 = wi & 63;
    int wh = w64 >> 3, ww = w64 & 7;
    int i = t / 7, j = t - i * 7;
    int hy = wh * 7 + i, wy = ww * 7 + j;
    int hx = hy + SHIFT3; if (hx >= HH) hx -= HH;
    int wx = wy + SHIFT3; if (wx >= HH) wx -= HH;
    return b * (HH * HH) + hx * HH + wx;
}

// ---------------- all four weight transposes in ONE launch ----------------
__global__ __launch_bounds__(256) void transpose_all(const float* __restrict__ qkv_w,
                                                     const float* __restrict__ proj_w,
                                                     const float* __restrict__ w1,
                                                     const float* __restrict__ w2,
                                                     bf16_t* __restrict__ wt_qkv,
                                                     bf16_t* __restrict__ wt_proj,
                                                     bf16_t* __restrict__ wt_mlp1,
                                                     bf16_t* __restrict__ wt_mlp2) {
    int t = blockIdx.x * 256 + threadIdx.x;
    const float* W; bf16_t* WT; int K, Nc;
    if (t < 196608)      { W = qkv_w;  WT = wt_qkv;  K = 256;  Nc = 768;  }
    else if (t < 262144) { W = proj_w; WT = wt_proj; K = 256;  Nc = 256;  t -= 196608; }
    else if (t < 524288) { W = w1;     WT = wt_mlp1; K = 256;  Nc = 1024; t -= 262144; }
    else                 { W = w2;     WT = wt_mlp2; K = 1024; Nc = 256;  t -= 524288; }
    int k = t / Nc, c = t - k * Nc;
    WT[(size_t)c * K + k] = (bf16_t)W[t];
}

// ---------------- LayerNorm (+optional window gather) + bf16 cast ----------------
template <int MAP>
__global__ __launch_bounds__(256) void ln_kernel(const float* __restrict__ x,
                                                 const float* __restrict__ g,
                                                 const float* __restrict__ bsh,
                                                 bf16_t* __restrict__ out) {
    int wv = threadIdx.x >> 6, l = threadIdx.x & 63;
    int r = blockIdx.x * 4 + wv;
    int xr = MAP ? xrow_of(r) : r;
    float4 v = ((const float4*)(x + (size_t)xr * DIMC))[l];
    float s = v.x + v.y + v.z + v.w;
    float sq = v.x * v.x + v.y * v.y + v.z * v.z + v.w * v.w;
    #pragma unroll
    for (int off = 32; off; off >>= 1) {
        s += __shfl_down(s, off);
        sq += __shfl_down(sq, off);
    }
    s = __shfl(s, 0); sq = __shfl(sq, 0);
    float mean = s * (1.f / 256.f);
    float var = sq * (1.f / 256.f) - mean * mean;
    float rstd = rsqrtf(var + 1e-5f);
    float4 gv = ((const float4*)g)[l];
    float4 bv = ((const float4*)bsh)[l];
    bf16x4 o;
    o[0] = (bf16_t)((v.x - mean) * rstd * gv.x + bv.x);
    o[1] = (bf16_t)((v.y - mean) * rstd * gv.y + bv.y);
    o[2] = (bf16_t)((v.z - mean) * rstd * gv.z + bv.z);
    o[3] = (bf16_t)((v.w - mean) * rstd * gv.w + bv.w);
    *(bf16x4*)(out + (size_t)r * DIMC + l * 4) = o;
}

// ---------------- pipelined bf16 MFMA GEMM: 256x256 tile, 1024 thr, BK=32, 3-buffer ----
// Per buffer (32KB): A region 16KB (256 rows x 64B) + B region 16KB (256 rows).
// Region layout (r10-verified 0-conflict): sup = row>>1 (128B super-rows),
// us = ((row&1)<<2)|chunk, slot = us ^ (sup&7); staging pre-applies inverse on the
// GLOBAL address, LDS dst linear. 16 waves as 4x4 grid of 64x64 wave-tiles.
// One barrier/step, stage s+2 at step top, vmcnt(2) steady / vmcnt(0) tail.
// EPI: 0 = bias, bf16 | 1 = bias+gelu, bf16 | 2 = bias+resid, f32 |
//      3 = bias + scatter to xrow_of(r) + resid, f32
template <int EPI, int KT>
__global__ __launch_bounds__(1024, 4) void gemm256(const bf16_t* __restrict__ A,
                                                   const bf16_t* __restrict__ BT,
                                                   const float* __restrict__ bias,
                                                   int Nc,
                                                   bf16_t* __restrict__ outb,
                                                   float* __restrict__ outf,
                                                   const float* __restrict__ resid) {
    constexpr int NS = KT / 32;
    __shared__ __align__(16) char S[3][32768];
    int tid = threadIdx.x;
    int wv = tid >> 6, l = tid & 63;
    int wr = wv >> 2, wc = wv & 3;
    int nTilesN = Nc >> 8;
    int qn = gridDim.x >> 3;
    int lb = (blockIdx.x & 7) * qn + (blockIdx.x >> 3);
    int bm = lb / nTilesN, bn = lb - bm * nTilesN;
    size_t row0 = (size_t)bm * 256;
    int col0 = bn * 256;

    const char* Abase = (const char*)(A + row0 * KT);
    const char* Bbase = (const char*)(BT + (size_t)col0 * KT);
    const size_t ldb = (size_t)KT * 2;

    // A: 1024 16B-chunks (1/thread), B: 1024 chunks (1/thread)
    auto STAGE = [&](int b, int kk) {
        int sup = tid >> 3, slot = tid & 7;
        int us = slot ^ (sup & 7);
        int row = 2 * sup + (us >> 2), ch = us & 3;
        __builtin_amdgcn_global_load_lds(
            (const __attribute__((address_space(1))) void*)(Abase + (size_t)row * ldb + (size_t)kk * 2 + ch * 16),
            (__attribute__((address_space(3))) void*)(S[b] + tid * 16), 16, 0, 0);
        __builtin_amdgcn_global_load_lds(
            (const __attribute__((address_space(1))) void*)(Bbase + (size_t)row * ldb + (size_t)kk * 2 + ch * 16),
            (__attribute__((address_space(3))) void*)(S[b] + 16384 + tid * 16), 16, 0, 0);
    };

    f32x4 acc[4][4] = {};
    const int lr = l & 15, g4 = l >> 4;

    STAGE(0, 0);
    STAGE(1, 32);

    #pragma unroll
    for (int s = 0; s < NS; ++s) {
        if (s + 1 < NS) { asm volatile("s_waitcnt vmcnt(2)" ::: "memory"); }
        else            { asm volatile("s_waitcnt vmcnt(0)" ::: "memory"); }
        __builtin_amdgcn_s_barrier();
        __builtin_amdgcn_sched_barrier(0);
        int buf = s % 3;
        if (s + 2 < NS) STAGE((s + 2) % 3, (s + 2) * 32);
        const char* Sb = S[buf];
        bf16x8 a[4], b[4];
        #pragma unroll
        for (int mt = 0; mt < 4; ++mt) {
            int r = wr * 64 + mt * 16 + lr;
            int sup = r >> 1;
            int us = ((r & 1) << 2) | g4;
            a[mt] = *(const bf16x8*)(Sb + sup * 128 + ((us ^ (sup & 7)) * 16));
        }
        #pragma unroll
        for (int nt = 0; nt < 4; ++nt) {
            int rc = wc * 64 + nt * 16 + lr;
            int sup = rc >> 1;
            int us = ((rc & 1) << 2) | g4;
            b[nt] = *(const bf16x8*)(Sb + 16384 + sup * 128 + ((us ^ (sup & 7)) * 16));
        }
        __builtin_amdgcn_s_setprio(1);
        #pragma unroll
        for (int mt = 0; mt < 4; ++mt)
            #pragma unroll
            for (int nt = 0; nt < 4; ++nt)
                acc[mt][nt] = __builtin_amdgcn_mfma_f32_16x16x32_bf16(a[mt], b[nt], acc[mt][nt], 0, 0, 0);
        __builtin_amdgcn_s_setprio(0);
        __builtin_amdgcn_sched_barrier(0);
    }

    #pragma unroll
    for (int m = 0; m < 4; ++m) {
        #pragma unroll
        for (int i = 0; i < 4; ++i) {
            int rr = (int)row0 + wr * 64 + m * 16 + g4 * 4 + i;
            size_t orow = (EPI == 3) ? (size_t)xrow_of(rr) * DIMC : (size_t)rr * Nc;
            #pragma unroll
            for (int n = 0; n < 4; ++n) {
                int cc = col0 + wc * 64 + n * 16 + lr;
                float v = acc[m][n][i] + bias[cc];
                if (EPI == 0) {
                    outb[(size_t)rr * Nc + cc] = (bf16_t)v;
                } else if (EPI == 1) {
                    float t3 = v + 0.044715f * v * v * v;
                    float e = __expf(-1.5957691216057308f * t3);
                    float gl = v * __builtin_amdgcn_rcpf(1.f + e);
                    outb[(size_t)rr * Nc + cc] = (bf16_t)gl;
                } else if (EPI == 2) {
                    size_t o = (size_t)rr * Nc + cc;
                    outf[o] = v + resid[o];
                } else {
                    size_t o = orow + cc;
                    outf[o] = v + resid[o];
                }
            }
        }
    }
}

// ---------------- MFMA windowed attention ----------------
__global__ __launch_bounds__(256) void attn_mfma(const bf16_t* __restrict__ qkv,
                                                 const float* __restrict__ bt,
                                                 bf16_t* __restrict__ out) {
    __shared__ __align__(16) char lds[4][12800];
    int wv = threadIdx.x >> 6, l = threadIdx.x & 63;
    int head = ((blockIdx.x & 1) << 2) | wv;
    int wi = blockIdx.x >> 1;
    char* W = lds[wv];
    bf16_t* Vt = (bf16_t*)(W + 8192);          // [32][72]
    size_t rowbase = (size_t)wi * NTOK;
    const bf16_t* src = qkv + rowbase * 768 + head * HD;

    int w64 = wi & 63;
    int wh = w64 >> 3, ww = w64 & 7;
    bool lastH = (wh == 7), lastW = (ww == 7);
    bool masked = lastH || lastW;

    #pragma unroll
    for (int it = 0; it < 4; ++it) {
        int t = l + it * 64;
        int r = t >> 2, g = t & 3;
        if (r < NTOK) {
            bf16x8 qv = *(const bf16x8*)(src + (size_t)r * 768 + g * 8);
            bf16x8 kv = *(const bf16x8*)(src + (size_t)r * 768 + 256 + g * 8);
            int sa = (r * 64 + g * 16) ^ ((r & 7) << 4);
            *(bf16x8*)(W + sa) = qv;
            *(bf16x8*)(W + 4096 + sa) = kv;
        }
    }
    #pragma unroll
    for (int it = 0; it < 4; ++it) {
        int t = l + it * 64;
        int m = t >> 2, dc = t & 3;
        if (m < NTOK) {
            bf16x8 vv = *(const bf16x8*)(src + (size_t)m * 768 + 512 + dc * 8);
            #pragma unroll
            for (int j = 0; j < 8; ++j) Vt[(dc * 8 + j) * 72 + m] = vv[j];
        } else {
            #pragma unroll
            for (int j = 0; j < 8; ++j) Vt[(dc * 8 + j) * 72 + m] = (bf16_t)0.f;
        }
    }

    int lr = l & 15, g4 = l >> 4;

    bf16x8 a[4], b[4];
    #pragma unroll
    for (int mt = 0; mt < 4; ++mt) {
        int r = mt * 16 + lr;
        int sa = (r * 64 + g4 * 16) ^ ((r & 7) << 4);
        a[mt] = *(const bf16x8*)(W + sa);
        b[mt] = *(const bf16x8*)(W + 4096 + sa);
    }
    f32x4 z = {0.f, 0.f, 0.f, 0.f};
    f32x4 S[4][4];
    #pragma unroll
    for (int mt = 0; mt < 4; ++mt)
        #pragma unroll
        for (int nt = 0; nt < 4; ++nt)
            S[mt][nt] = __builtin_amdgcn_mfma_f32_16x16x32_bf16(a[mt], b[nt], z, 0, 0, 0);

    int i2[4], j2[4], reg2[4];
    #pragma unroll
    for (int nt = 0; nt < 4; ++nt) {
        int cm = nt * 16 + lr;
        i2[nt] = (cm * 147) >> 10;
        j2[nt] = cm - i2[nt] * 7;
        int rh = lastH ? ((i2[nt] < 4) ? 1 : 2) : 0;
        int rw = lastW ? ((j2[nt] < 4) ? 1 : 2) : 0;
        reg2[nt] = rh * 3 + rw;
    }

    #pragma unroll
    for (int mt = 0; mt < 4; ++mt) {
        #pragma unroll
        for (int i = 0; i < 4; ++i) {
            int rn = mt * 16 + g4 * 4 + i;
            bool rowok = rn < NTOK;
            int i1 = (rn * 147) >> 10, j1 = rn - i1 * 7;
            int rh1 = lastH ? ((i1 < 4) ? 1 : 2) : 0;
            int rw1 = lastW ? ((j1 < 4) ? 1 : 2) : 0;
            int reg1 = rh1 * 3 + rw1;
            float sv[4];
            #pragma unroll
            for (int nt = 0; nt < 4; ++nt) {
                int cm = nt * 16 + lr;
                float sc;
                if (rowok && cm < NTOK) {
                    sc = S[mt][nt][i] * SCALE_QK;
                    sc += bt[((i1 - i2[nt] + 6) + 13 * (j1 - j2[nt] + 6)) * 8 + head];
                    if (masked && (reg1 != reg2[nt])) sc -= 100.f;
                } else {
                    sc = -1e30f;
                }
                sv[nt] = sc;
            }
            float mx = fmaxf(fmaxf(sv[0], sv[1]), fmaxf(sv[2], sv[3]));
            mx = fmaxf(mx, __shfl_xor(mx, 1));
            mx = fmaxf(mx, __shfl_xor(mx, 2));
            mx = fmaxf(mx, __shfl_xor(mx, 4));
            mx = fmaxf(mx, __shfl_xor(mx, 8));
            float e[4];
            float sum = 0.f;
            #pragma unroll
            for (int nt = 0; nt < 4; ++nt) { e[nt] = __expf(sv[nt] - mx); sum += e[nt]; }
            sum += __shfl_xor(sum, 1);
            sum += __shfl_xor(sum, 2);
            sum += __shfl_xor(sum, 4);
            sum += __shfl_xor(sum, 8);
            float inv = 1.f / sum;
            #pragma unroll
            for (int nt = 0; nt < 4; ++nt) {
                int cm = nt * 16 + lr;
                int pa = (rn * 128 + cm * 2) ^ ((rn & 7) << 4);
                *(bf16_t*)(W + pa) = (bf16_t)(e[nt] * inv);
            }
        }
    }

    f32x4 o[4][2] = {};
    #pragma unroll
    for (int ks = 0; ks < 2; ++ks) {
        bf16x8 pa[4], vb[2];
        #pragma unroll
        for (int mt = 0; mt < 4; ++mt) {
            int r = mt * 16 + lr;
            int ad = (r * 128 + ks * 64 + g4 * 16) ^ ((r & 7) << 4);
            pa[mt] = *(const bf16x8*)(W + ad);
        }
        #pragma unroll
        for (int dt = 0; dt < 2; ++dt) {
            int d = dt * 16 + lr;
            vb[dt] = *(const bf16x8*)((char*)Vt + d * 144 + ks * 64 + g4 * 16);
        }
        #pragma unroll
        for (int mt = 0; mt < 4; ++mt)
            #pragma unroll
            for (int dt = 0; dt < 2; ++dt)
                o[mt][dt] = __builtin_amdgcn_mfma_f32_16x16x32_bf16(pa[mt], vb[dt], o[mt][dt], 0, 0, 0);
    }

    #pragma unroll
    for (int mt = 0; mt < 4; ++mt) {
        #pragma unroll
        for (int i = 0; i < 4; ++i) {
            int n = mt * 16 + g4 * 4 + i;
            if (n < NTOK) {
                #pragma unroll
                for (int dt = 0; dt < 2; ++dt) {
                    out[(rowbase + n) * DIMC + head * HD + dt * 16 + lr] = (bf16_t)o[mt][dt][i];
                }
            }
        }
    }
}

extern "C" void kernel_launch(void* const* d_in, const int* in_sizes, int n_in,
                              void* d_out, int out_size, void* d_ws, size_t ws_size,
                              hipStream_t stream) {
    const float* x      = (const float*)d_in[0];
    const float* n1g    = (const float*)d_in[1];
    const float* n1b    = (const float*)d_in[2];
    const float* qkv_w  = (const float*)d_in[3];
    const float* qkv_b  = (const float*)d_in[4];
    const float* proj_w = (const float*)d_in[5];
    const float* proj_b = (const float*)d_in[6];
    const float* btab   = (const float*)d_in[7];
    const float* n2g    = (const float*)d_in[8];
    const float* n2b    = (const float*)d_in[9];
    const float* w1     = (const float*)d_in[10];
    const float* b1     = (const float*)d_in[11];
    const float* w2     = (const float*)d_in[12];
    const float* b2     = (const float*)d_in[13];

    char* ws = (char*)d_ws;
    bf16_t* win      = (bf16_t*)(ws);
    bf16_t* qkvbuf   = (bf16_t*)(ws + (size_t)T_TOK * 256 * 2);
    bf16_t* mlp1_buf = (bf16_t*)(ws);                       // aliases win+qkvbuf after proj
    bf16_t* h2       = (bf16_t*)(ws + (size_t)T_TOK * 2048);
    char* wtp        = ws + (size_t)T_TOK * 2048 + (size_t)T_TOK * 512;
    bf16_t* wt_qkv   = (bf16_t*)wtp;               // [768][256]
    bf16_t* wt_proj  = wt_qkv + 768 * 256;         // [256][256]
    bf16_t* wt_mlp1  = wt_proj + 256 * 256;        // [1024][256]
    bf16_t* wt_mlp2  = wt_mlp1 + 1024 * 256;       // [256][1024]
    float* xmid      = (float*)d_out;

    // all weight transposes in one launch (786432 elements / 256)
    transpose_all<<<3072, 256, 0, stream>>>(qkv_w, proj_w, w1, w2,
                                            wt_qkv, wt_proj, wt_mlp1, wt_mlp2);

    // LN1 + shift + window partition
    ln_kernel<1><<<T_TOK / 4, 256, 0, stream>>>(x, n1g, n1b, win);
    // QKV GEMM  [T,256] x [256,768]
    gemm256<0, 256><<<(T_TOK / 256) * (768 / 256), 1024, 0, stream>>>(win, wt_qkv, qkv_b, 768,
                                                                      qkvbuf, nullptr, nullptr);
    attn_mfma<<<2048 * 2, 256, 0, stream>>>(qkvbuf, btab, win);
    // proj GEMM + window reverse + unshift + residual -> xmid (= d_out)
    gemm256<3, 256><<<(T_TOK / 256) * (256 / 256), 1024, 0, stream>>>(win, wt_proj, proj_b, 256,
                                                                      nullptr, xmid, x);
    // LN2
    ln_kernel<0><<<T_TOK / 4, 256, 0, stream>>>(xmid, n2g, n2b, h2);
    // MLP1 + GELU  [T,256] x [256,1024]
    gemm256<1, 256><<<(T_TOK / 256) * (1024 / 256), 1024, 0, stream>>>(h2, wt_mlp1, b1, 1024,
                                                                       mlp1_buf, nullptr, nullptr);
    // MLP2 + residual  [T,1024] x [1024,256] -> d_out
    gemm256<2, 1024><<<(T_TOK / 256) * (256 / 256), 1024, 0, stream>>>(mlp1_buf, wt_mlp2, b2, 256,
                                                                       nullptr, xmid, xmid);
}

// Round 14
// 498.869 us; speedup vs baseline: 1.0250x; 1.0250x over previous
//
#include <hip/hip_runtime.h>
#include <hip/hip_bf16.h>
#include <math.h>

typedef __bf16 bf16_t;
typedef __attribute__((ext_vector_type(8))) __bf16 bf16x8;
typedef __attribute__((ext_vector_type(4))) __bf16 bf16x4;
typedef __attribute__((ext_vector_type(4))) float f32x4;

#define T_TOK 100352      // 32 * 3136 tokens (= Bw*N = 2048*49)
#define DIMC 256
#define HEADS 8
#define HD 32
#define NTOK 49
#define SHIFT3 3
#define HH 56
#define SCALE_QK 0.17677669529663687f

__device__ __forceinline__ int xrow_of(int rr) {
    int wi = rr / 49; int t = rr - wi * 49;
    int b = wi >> 6; int w64 = wi & 63;
    int wh = w64 >> 3, ww = w64 & 7;
    int i = t / 7, j = t - i * 7;
    int hy = wh * 7 + i, wy = ww * 7 + j;
    int hx = hy + SHIFT3; if (hx >= HH) hx -= HH;
    int wx = wy + SHIFT3; if (wx >= HH) wx -= HH;
    return b * (HH * HH) + hx * HH + wx;
}

// ---------------- all four weight transposes in ONE launch ----------------
__global__ __launch_bounds__(256) void transpose_all(const float* __restrict__ qkv_w,
                                                     const float* __restrict__ proj_w,
                                                     const float* __restrict__ w1,
                                                     const float* __restrict__ w2,
                                                     bf16_t* __restrict__ wt_qkv,
                                                     bf16_t* __restrict__ wt_proj,
                                                     bf16_t* __restrict__ wt_mlp1,
                                                     bf16_t* __restrict__ wt_mlp2) {
    int t = blockIdx.x * 256 + threadIdx.x;
    const float* W; bf16_t* WT; int K, Nc;
    if (t < 196608)      { W = qkv_w;  WT = wt_qkv;  K = 256;  Nc = 768;  }
    else if (t < 262144) { W = proj_w; WT = wt_proj; K = 256;  Nc = 256;  t -= 196608; }
    else if (t < 524288) { W = w1;     WT = wt_mlp1; K = 256;  Nc = 1024; t -= 262144; }
    else                 { W = w2;     WT = wt_mlp2; K = 1024; Nc = 256;  t -= 524288; }
    int k = t / Nc, c = t - k * Nc;
    WT[(size_t)c * K + k] = (bf16_t)W[t];
}

// ---------------- LayerNorm (+optional window gather) + bf16 cast ----------------
template <int MAP>
__global__ __launch_bounds__(256) void ln_kernel(const float* __restrict__ x,
                                                 const float* __restrict__ g,
                                                 const float* __restrict__ bsh,
                                                 bf16_t* __restrict__ out) {
    int wv = threadIdx.x >> 6, l = threadIdx.x & 63;
    int r = blockIdx.x * 4 + wv;
    int xr = MAP ? xrow_of(r) : r;
    float4 v = ((const float4*)(x + (size_t)xr * DIMC))[l];
    float s = v.x + v.y + v.z + v.w;
    float sq = v.x * v.x + v.y * v.y + v.z * v.z + v.w * v.w;
    #pragma unroll
    for (int off = 32; off; off >>= 1) {
        s += __shfl_down(s, off);
        sq += __shfl_down(sq, off);
    }
    s = __shfl(s, 0); sq = __shfl(sq, 0);
    float mean = s * (1.f / 256.f);
    float var = sq * (1.f / 256.f) - mean * mean;
    float rstd = rsqrtf(var + 1e-5f);
    float4 gv = ((const float4*)g)[l];
    float4 bv = ((const float4*)bsh)[l];
    bf16x4 o;
    o[0] = (bf16_t)((v.x - mean) * rstd * gv.x + bv.x);
    o[1] = (bf16_t)((v.y - mean) * rstd * gv.y + bv.y);
    o[2] = (bf16_t)((v.z - mean) * rstd * gv.z + bv.z);
    o[3] = (bf16_t)((v.w - mean) * rstd * gv.w + bv.w);
    *(bf16x4*)(out + (size_t)r * DIMC + l * 4) = o;
}

// ---------------- gemm_a: 128x256 tile, 512 thr, BK=32, 3-buffer (r12-validated) ------
// EPI: 0 = bias, bf16 | 1 = bias+gelu, bf16 | 2 = bias+resid, f32 |
//      3 = bias + scatter to xrow_of(r) + resid, f32
template <int EPI, int KT>
__global__ __launch_bounds__(512, 4) void gemm_a(const bf16_t* __restrict__ A,
                                                 const bf16_t* __restrict__ BT,
                                                 const float* __restrict__ bias,
                                                 int Nc,
                                                 bf16_t* __restrict__ outb,
                                                 float* __restrict__ outf,
                                                 const float* __restrict__ resid) {
    constexpr int NS = KT / 32;
    __shared__ __align__(16) char S[3][24576];
    int tid = threadIdx.x;
    int wv = tid >> 6, l = tid & 63;
    int wr = wv >> 2, wc = wv & 3;
    int nTilesN = Nc >> 8;
    int qn = gridDim.x >> 3;
    int lb = (blockIdx.x & 7) * qn + (blockIdx.x >> 3);
    int bm = lb / nTilesN, bn = lb - bm * nTilesN;
    size_t row0 = (size_t)bm * 128;
    int col0 = bn * 256;

    const char* Abase = (const char*)(A + row0 * KT);
    const char* Bbase = (const char*)(BT + (size_t)col0 * KT);
    const size_t ldb = (size_t)KT * 2;

    auto STAGE = [&](int b, int kk) {
        {
            int ci = tid;
            int sup = ci >> 3, slot = ci & 7;
            int us = slot ^ (sup & 7);
            int row = 2 * sup + (us >> 2), ch = us & 3;
            __builtin_amdgcn_global_load_lds(
                (const __attribute__((address_space(1))) void*)(Abase + (size_t)row * ldb + (size_t)kk * 2 + ch * 16),
                (__attribute__((address_space(3))) void*)(S[b] + ci * 16), 16, 0, 0);
        }
        #pragma unroll
        for (int it = 0; it < 2; ++it) {
            int ci = tid + it * 512;
            int sup = ci >> 3, slot = ci & 7;
            int us = slot ^ (sup & 7);
            int row = 2 * sup + (us >> 2), ch = us & 3;
            __builtin_amdgcn_global_load_lds(
                (const __attribute__((address_space(1))) void*)(Bbase + (size_t)row * ldb + (size_t)kk * 2 + ch * 16),
                (__attribute__((address_space(3))) void*)(S[b] + 8192 + ci * 16), 16, 0, 0);
        }
    };

    f32x4 acc[4][4] = {};
    const int lr = l & 15, g4 = l >> 4;

    STAGE(0, 0);
    STAGE(1, 32);

    #pragma unroll
    for (int s = 0; s < NS; ++s) {
        if (s + 1 < NS) { asm volatile("s_waitcnt vmcnt(3)" ::: "memory"); }
        else            { asm volatile("s_waitcnt vmcnt(0)" ::: "memory"); }
        __builtin_amdgcn_s_barrier();
        __builtin_amdgcn_sched_barrier(0);
        int buf = s % 3;
        if (s + 2 < NS) STAGE((s + 2) % 3, (s + 2) * 32);
        const char* Sb = S[buf];
        bf16x8 a[4], b[4];
        #pragma unroll
        for (int mt = 0; mt < 4; ++mt) {
            int r = wr * 64 + mt * 16 + lr;
            int sup = r >> 1;
            int us = ((r & 1) << 2) | g4;
            a[mt] = *(const bf16x8*)(Sb + sup * 128 + ((us ^ (sup & 7)) * 16));
        }
        #pragma unroll
        for (int nt = 0; nt < 4; ++nt) {
            int rc = wc * 64 + nt * 16 + lr;
            int sup = rc >> 1;
            int us = ((rc & 1) << 2) | g4;
            b[nt] = *(const bf16x8*)(Sb + 8192 + sup * 128 + ((us ^ (sup & 7)) * 16));
        }
        __builtin_amdgcn_s_setprio(1);
        #pragma unroll
        for (int mt = 0; mt < 4; ++mt)
            #pragma unroll
            for (int nt = 0; nt < 4; ++nt)
                acc[mt][nt] = __builtin_amdgcn_mfma_f32_16x16x32_bf16(a[mt], b[nt], acc[mt][nt], 0, 0, 0);
        __builtin_amdgcn_s_setprio(0);
        __builtin_amdgcn_sched_barrier(0);
    }

    #pragma unroll
    for (int m = 0; m < 4; ++m) {
        #pragma unroll
        for (int i = 0; i < 4; ++i) {
            int rr = (int)row0 + wr * 64 + m * 16 + g4 * 4 + i;
            size_t orow = (EPI == 3) ? (size_t)xrow_of(rr) * DIMC : (size_t)rr * Nc;
            #pragma unroll
            for (int n = 0; n < 4; ++n) {
                int cc = col0 + wc * 64 + n * 16 + lr;
                float v = acc[m][n][i] + bias[cc];
                if (EPI == 0) {
                    outb[(size_t)rr * Nc + cc] = (bf16_t)v;
                } else if (EPI == 1) {
                    float t3 = v + 0.044715f * v * v * v;
                    float e = __expf(-1.5957691216057308f * t3);
                    float gl = v * __builtin_amdgcn_rcpf(1.f + e);
                    outb[(size_t)rr * Nc + cc] = (bf16_t)gl;
                } else if (EPI == 2) {
                    size_t o = (size_t)rr * Nc + cc;
                    outf[o] = v + resid[o];
                } else {
                    size_t o = orow + cc;
                    outf[o] = v + resid[o];
                }
            }
        }
    }
}

// ---------------- gemm_b: 256x256 tile, 1024 thr, BK=32, 3-buffer (r13-validated) -----
template <int EPI, int KT>
__global__ __launch_bounds__(1024, 4) void gemm_b(const bf16_t* __restrict__ A,
                                                  const bf16_t* __restrict__ BT,
                                                  const float* __restrict__ bias,
                                                  int Nc,
                                                  bf16_t* __restrict__ outb,
                                                  float* __restrict__ outf,
                                                  const float* __restrict__ resid) {
    constexpr int NS = KT / 32;
    __shared__ __align__(16) char S[3][32768];
    int tid = threadIdx.x;
    int wv = tid >> 6, l = tid & 63;
    int wr = wv >> 2, wc = wv & 3;
    int nTilesN = Nc >> 8;
    int qn = gridDim.x >> 3;
    int lb = (blockIdx.x & 7) * qn + (blockIdx.x >> 3);
    int bm = lb / nTilesN, bn = lb - bm * nTilesN;
    size_t row0 = (size_t)bm * 256;
    int col0 = bn * 256;

    const char* Abase = (const char*)(A + row0 * KT);
    const char* Bbase = (const char*)(BT + (size_t)col0 * KT);
    const size_t ldb = (size_t)KT * 2;

    auto STAGE = [&](int b, int kk) {
        int sup = tid >> 3, slot = tid & 7;
        int us = slot ^ (sup & 7);
        int row = 2 * sup + (us >> 2), ch = us & 3;
        __builtin_amdgcn_global_load_lds(
            (const __attribute__((address_space(1))) void*)(Abase + (size_t)row * ldb + (size_t)kk * 2 + ch * 16),
            (__attribute__((address_space(3))) void*)(S[b] + tid * 16), 16, 0, 0);
        __builtin_amdgcn_global_load_lds(
            (const __attribute__((address_space(1))) void*)(Bbase + (size_t)row * ldb + (size_t)kk * 2 + ch * 16),
            (__attribute__((address_space(3))) void*)(S[b] + 16384 + tid * 16), 16, 0, 0);
    };

    f32x4 acc[4][4] = {};
    const int lr = l & 15, g4 = l >> 4;

    STAGE(0, 0);
    STAGE(1, 32);

    #pragma unroll
    for (int s = 0; s < NS; ++s) {
        if (s + 1 < NS) { asm volatile("s_waitcnt vmcnt(2)" ::: "memory"); }
        else            { asm volatile("s_waitcnt vmcnt(0)" ::: "memory"); }
        __builtin_amdgcn_s_barrier();
        __builtin_amdgcn_sched_barrier(0);
        int buf = s % 3;
        if (s + 2 < NS) STAGE((s + 2) % 3, (s + 2) * 32);
        const char* Sb = S[buf];
        bf16x8 a[4], b[4];
        #pragma unroll
        for (int mt = 0; mt < 4; ++mt) {
            int r = wr * 64 + mt * 16 + lr;
            int sup = r >> 1;
            int us = ((r & 1) << 2) | g4;
            a[mt] = *(const bf16x8*)(Sb + sup * 128 + ((us ^ (sup & 7)) * 16));
        }
        #pragma unroll
        for (int nt = 0; nt < 4; ++nt) {
            int rc = wc * 64 + nt * 16 + lr;
            int sup = rc >> 1;
            int us = ((rc & 1) << 2) | g4;
            b[nt] = *(const bf16x8*)(Sb + 16384 + sup * 128 + ((us ^ (sup & 7)) * 16));
        }
        __builtin_amdgcn_s_setprio(1);
        #pragma unroll
        for (int mt = 0; mt < 4; ++mt)
            #pragma unroll
            for (int nt = 0; nt < 4; ++nt)
                acc[mt][nt] = __builtin_amdgcn_mfma_f32_16x16x32_bf16(a[mt], b[nt], acc[mt][nt], 0, 0, 0);
        __builtin_amdgcn_s_setprio(0);
        __builtin_amdgcn_sched_barrier(0);
    }

    #pragma unroll
    for (int m = 0; m < 4; ++m) {
        #pragma unroll
        for (int i = 0; i < 4; ++i) {
            int rr = (int)row0 + wr * 64 + m * 16 + g4 * 4 + i;
            size_t orow = (EPI == 3) ? (size_t)xrow_of(rr) * DIMC : (size_t)rr * Nc;
            #pragma unroll
            for (int n = 0; n < 4; ++n) {
                int cc = col0 + wc * 64 + n * 16 + lr;
                float v = acc[m][n][i] + bias[cc];
                if (EPI == 0) {
                    outb[(size_t)rr * Nc + cc] = (bf16_t)v;
                } else if (EPI == 1) {
                    float t3 = v + 0.044715f * v * v * v;
                    float e = __expf(-1.5957691216057308f * t3);
                    float gl = v * __builtin_amdgcn_rcpf(1.f + e);
                    outb[(size_t)rr * Nc + cc] = (bf16_t)gl;
                } else if (EPI == 2) {
                    size_t o = (size_t)rr * Nc + cc;
                    outf[o] = v + resid[o];
                } else {
                    size_t o = orow + cc;
                    outf[o] = v + resid[o];
                }
            }
        }
    }
}

// ---------------- MFMA windowed attention ----------------
__global__ __launch_bounds__(256) void attn_mfma(const bf16_t* __restrict__ qkv,
                                                 const float* __restrict__ bt,
                                                 bf16_t* __restrict__ out) {
    __shared__ __align__(16) char lds[4][12800];
    int wv = threadIdx.x >> 6, l = threadIdx.x & 63;
    int head = ((blockIdx.x & 1) << 2) | wv;
    int wi = blockIdx.x >> 1;
    char* W = lds[wv];
    bf16_t* Vt = (bf16_t*)(W + 8192);          // [32][72]
    size_t rowbase = (size_t)wi * NTOK;
    const bf16_t* src = qkv + rowbase * 768 + head * HD;

    int w64 = wi & 63;
    int wh = w64 >> 3, ww = w64 & 7;
    bool lastH = (wh == 7), lastW = (ww == 7);
    bool masked = lastH || lastW;

    #pragma unroll
    for (int it = 0; it < 4; ++it) {
        int t = l + it * 64;
        int r = t >> 2, g = t & 3;
        if (r < NTOK) {
            bf16x8 qv = *(const bf16x8*)(src + (size_t)r * 768 + g * 8);
            bf16x8 kv = *(const bf16x8*)(src + (size_t)r * 768 + 256 + g * 8);
            int sa = (r * 64 + g * 16) ^ ((r & 7) << 4);
            *(bf16x8*)(W + sa) = qv;
            *(bf16x8*)(W + 4096 + sa) = kv;
        }
    }
    #pragma unroll
    for (int it = 0; it < 4; ++it) {
        int t = l + it * 64;
        int m = t >> 2, dc = t & 3;
        if (m < NTOK) {
            bf16x8 vv = *(const bf16x8*)(src + (size_t)m * 768 + 512 + dc * 8);
            #pragma unroll
            for (int j = 0; j < 8; ++j) Vt[(dc * 8 + j) * 72 + m] = vv[j];
        } else {
            #pragma unroll
            for (int j = 0; j < 8; ++j) Vt[(dc * 8 + j) * 72 + m] = (bf16_t)0.f;
        }
    }

    int lr = l & 15, g4 = l >> 4;

    bf16x8 a[4], b[4];
    #pragma unroll
    for (int mt = 0; mt < 4; ++mt) {
        int r = mt * 16 + lr;
        int sa = (r * 64 + g4 * 16) ^ ((r & 7) << 4);
        a[mt] = *(const bf16x8*)(W + sa);
        b[mt] = *(const bf16x8*)(W + 4096 + sa);
    }
    f32x4 z = {0.f, 0.f, 0.f, 0.f};
    f32x4 S[4][4];
    #pragma unroll
    for (int mt = 0; mt < 4; ++mt)
        #pragma unroll
        for (int nt = 0; nt < 4; ++nt)
            S[mt][nt] = __builtin_amdgcn_mfma_f32_16x16x32_bf16(a[mt], b[nt], z, 0, 0, 0);

    int i2[4], j2[4], reg2[4];
    #pragma unroll
    for (int nt = 0; nt < 4; ++nt) {
        int cm = nt * 16 + lr;
        i2[nt] = (cm * 147) >> 10;
        j2[nt] = cm - i2[nt] * 7;
        int rh = lastH ? ((i2[nt] < 4) ? 1 : 2) : 0;
        int rw = lastW ? ((j2[nt] < 4) ? 1 : 2) : 0;
        reg2[nt] = rh * 3 + rw;
    }

    #pragma unroll
    for (int mt = 0; mt < 4; ++mt) {
        #pragma unroll
        for (int i = 0; i < 4; ++i) {
            int rn = mt * 16 + g4 * 4 + i;
            bool rowok = rn < NTOK;
            int i1 = (rn * 147) >> 10, j1 = rn - i1 * 7;
            int rh1 = lastH ? ((i1 < 4) ? 1 : 2) : 0;
            int rw1 = lastW ? ((j1 < 4) ? 1 : 2) : 0;
            int reg1 = rh1 * 3 + rw1;
            float sv[4];
            #pragma unroll
            for (int nt = 0; nt < 4; ++nt) {
                int cm = nt * 16 + lr;
                float sc;
                if (rowok && cm < NTOK) {
                    sc = S[mt][nt][i] * SCALE_QK;
                    sc += bt[((i1 - i2[nt] + 6) + 13 * (j1 - j2[nt] + 6)) * 8 + head];
                    if (masked && (reg1 != reg2[nt])) sc -= 100.f;
                } else {
                    sc = -1e30f;
                }
                sv[nt] = sc;
            }
            float mx = fmaxf(fmaxf(sv[0], sv[1]), fmaxf(sv[2], sv[3]));
            mx = fmaxf(mx, __shfl_xor(mx, 1));
            mx = fmaxf(mx, __shfl_xor(mx, 2));
            mx = fmaxf(mx, __shfl_xor(mx, 4));
            mx = fmaxf(mx, __shfl_xor(mx, 8));
            float e[4];
            float sum = 0.f;
            #pragma unroll
            for (int nt = 0; nt < 4; ++nt) { e[nt] = __expf(sv[nt] - mx); sum += e[nt]; }
            sum += __shfl_xor(sum, 1);
            sum += __shfl_xor(sum, 2);
            sum += __shfl_xor(sum, 4);
            sum += __shfl_xor(sum, 8);
            float inv = 1.f / sum;
            #pragma unroll
            for (int nt = 0; nt < 4; ++nt) {
                int cm = nt * 16 + lr;
                int pa = (rn * 128 + cm * 2) ^ ((rn & 7) << 4);
                *(bf16_t*)(W + pa) = (bf16_t)(e[nt] * inv);
            }
        }
    }

    f32x4 o[4][2] = {};
    #pragma unroll
    for (int ks = 0; ks < 2; ++ks) {
        bf16x8 pa[4], vb[2];
        #pragma unroll
        for (int mt = 0; mt < 4; ++mt) {
            int r = mt * 16 + lr;
            int ad = (r * 128 + ks * 64 + g4 * 16) ^ ((r & 7) << 4);
            pa[mt] = *(const bf16x8*)(W + ad);
        }
        #pragma unroll
        for (int dt = 0; dt < 2; ++dt) {
            int d = dt * 16 + lr;
            vb[dt] = *(const bf16x8*)((char*)Vt + d * 144 + ks * 64 + g4 * 16);
        }
        #pragma unroll
        for (int mt = 0; mt < 4; ++mt)
            #pragma unroll
            for (int dt = 0; dt < 2; ++dt)
                o[mt][dt] = __builtin_amdgcn_mfma_f32_16x16x32_bf16(pa[mt], vb[dt], o[mt][dt], 0, 0, 0);
    }

    #pragma unroll
    for (int mt = 0; mt < 4; ++mt) {
        #pragma unroll
        for (int i = 0; i < 4; ++i) {
            int n = mt * 16 + g4 * 4 + i;
            if (n < NTOK) {
                #pragma unroll
                for (int dt = 0; dt < 2; ++dt) {
                    out[(rowbase + n) * DIMC + head * HD + dt * 16 + lr] = (bf16_t)o[mt][dt][i];
                }
            }
        }
    }
}

extern "C" void kernel_launch(void* const* d_in, const int* in_sizes, int n_in,
                              void* d_out, int out_size, void* d_ws, size_t ws_size,
                              hipStream_t stream) {
    const float* x      = (const float*)d_in[0];
    const float* n1g    = (const float*)d_in[1];
    const float* n1b    = (const float*)d_in[2];
    const float* qkv_w  = (const float*)d_in[3];
    const float* qkv_b  = (const float*)d_in[4];
    const float* proj_w = (const float*)d_in[5];
    const float* proj_b = (const float*)d_in[6];
    const float* btab   = (const float*)d_in[7];
    const float* n2g    = (const float*)d_in[8];
    const float* n2b    = (const float*)d_in[9];
    const float* w1     = (const float*)d_in[10];
    const float* b1     = (const float*)d_in[11];
    const float* w2     = (const float*)d_in[12];
    const float* b2     = (const float*)d_in[13];

    char* ws = (char*)d_ws;
    bf16_t* win      = (bf16_t*)(ws);
    bf16_t* qkvbuf   = (bf16_t*)(ws + (size_t)T_TOK * 256 * 2);
    bf16_t* mlp1_buf = (bf16_t*)(ws);                       // aliases win+qkvbuf after proj
    bf16_t* h2       = (bf16_t*)(ws + (size_t)T_TOK * 2048);
    char* wtp        = ws + (size_t)T_TOK * 2048 + (size_t)T_TOK * 512;
    bf16_t* wt_qkv   = (bf16_t*)wtp;               // [768][256]
    bf16_t* wt_proj  = wt_qkv + 768 * 256;         // [256][256]
    bf16_t* wt_mlp1  = wt_proj + 256 * 256;        // [1024][256]
    bf16_t* wt_mlp2  = wt_mlp1 + 1024 * 256;       // [256][1024]
    float* xmid      = (float*)d_out;

    // all weight transposes in one launch (786432 elements / 256)
    transpose_all<<<3072, 256, 0, stream>>>(qkv_w, proj_w, w1, w2,
                                            wt_qkv, wt_proj, wt_mlp1, wt_mlp2);

    // LN1 + shift + window partition
    ln_kernel<1><<<T_TOK / 4, 256, 0, stream>>>(x, n1g, n1b, win);
    // QKV GEMM  [T,256] x [256,768]  (K=256 -> gemm_a)
    gemm_a<0, 256><<<(T_TOK / 128) * (768 / 256), 512, 0, stream>>>(win, wt_qkv, qkv_b, 768,
                                                                    qkvbuf, nullptr, nullptr);
    attn_mfma<<<2048 * 2, 256, 0, stream>>>(qkvbuf, btab, win);
    // proj GEMM + window reverse + unshift + residual -> xmid (= d_out)  (K=256 -> gemm_a)
    gemm_a<3, 256><<<(T_TOK / 128) * (256 / 256), 512, 0, stream>>>(win, wt_proj, proj_b, 256,
                                                                    nullptr, xmid, x);
    // LN2
    ln_kernel<0><<<T_TOK / 4, 256, 0, stream>>>(xmid, n2g, n2b, h2);
    // MLP1 + GELU  [T,256] x [256,1024]  (K=256 -> gemm_a)
    gemm_a<1, 256><<<(T_TOK / 128) * (1024 / 256), 512, 0, stream>>>(h2, wt_mlp1, b1, 1024,
                                                                     mlp1_buf, nullptr, nullptr);
    // MLP2 + residual  [T,1024] x [1024,256] -> d_out  (K=1024 -> gemm_b, steady-state)
    gemm_b<2, 1024><<<(T_TOK / 256) * (256 / 256), 1024, 0, stream>>>(mlp1_buf, wt_mlp2, b2, 256,
                                                                      nullptr, xmid, xmid);
}

// Round 15
// 494.221 us; speedup vs baseline: 1.0346x; 1.0094x over previous
//
#include <hip/hip_runtime.h>
#include <hip/hip_bf16.h>
#include <math.h>

typedef __bf16 bf16_t;
typedef __attribute__((ext_vector_type(8))) __bf16 bf16x8;
typedef __attribute__((ext_vector_type(4))) __bf16 bf16x4;
typedef __attribute__((ext_vector_type(4))) float f32x4;

#define T_TOK 100352      // 32 * 3136 tokens (= Bw*N = 2048*49)
#define DIMC 256
#define HEADS 8
#define HD 32
#define NTOK 49
#define SHIFT3 3
#define HH 56
#define SCALE_QK 0.17677669529663687f

__device__ __forceinline__ int xrow_of(int rr) {
    int wi = rr / 49; int t = rr - wi * 49;
    int b = wi >> 6; int w64 = wi & 63;
    int wh = w64 >> 3, ww = w64 & 7;
    int i = t / 7, j = t - i * 7;
    int hy = wh * 7 + i, wy = ww * 7 + j;
    int hx = hy + SHIFT3; if (hx >= HH) hx -= HH;
    int wx = wy + SHIFT3; if (wx >= HH) wx -= HH;
    return b * (HH * HH) + hx * HH + wx;
}

// ---------------- all four weight transposes in ONE launch ----------------
__global__ __launch_bounds__(256) void transpose_all(const float* __restrict__ qkv_w,
                                                     const float* __restrict__ proj_w,
                                                     const float* __restrict__ w1,
                                                     const float* __restrict__ w2,
                                                     bf16_t* __restrict__ wt_qkv,
                                                     bf16_t* __restrict__ wt_proj,
                                                     bf16_t* __restrict__ wt_mlp1,
                                                     bf16_t* __restrict__ wt_mlp2) {
    int t = blockIdx.x * 256 + threadIdx.x;
    const float* W; bf16_t* WT; int K, Nc;
    if (t < 196608)      { W = qkv_w;  WT = wt_qkv;  K = 256;  Nc = 768;  }
    else if (t < 262144) { W = proj_w; WT = wt_proj; K = 256;  Nc = 256;  t -= 196608; }
    else if (t < 524288) { W = w1;     WT = wt_mlp1; K = 256;  Nc = 1024; t -= 262144; }
    else                 { W = w2;     WT = wt_mlp2; K = 1024; Nc = 256;  t -= 524288; }
    int k = t / Nc, c = t - k * Nc;
    WT[(size_t)c * K + k] = (bf16_t)W[t];
}

// ---------------- LayerNorm (+optional window gather) + bf16 cast ----------------
template <int MAP>
__global__ __launch_bounds__(256) void ln_kernel(const float* __restrict__ x,
                                                 const float* __restrict__ g,
                                                 const float* __restrict__ bsh,
                                                 bf16_t* __restrict__ out) {
    int wv = threadIdx.x >> 6, l = threadIdx.x & 63;
    int r = blockIdx.x * 4 + wv;
    int xr = MAP ? xrow_of(r) : r;
    float4 v = ((const float4*)(x + (size_t)xr * DIMC))[l];
    float s = v.x + v.y + v.z + v.w;
    float sq = v.x * v.x + v.y * v.y + v.z * v.z + v.w * v.w;
    #pragma unroll
    for (int off = 32; off; off >>= 1) {
        s += __shfl_down(s, off);
        sq += __shfl_down(sq, off);
    }
    s = __shfl(s, 0); sq = __shfl(sq, 0);
    float mean = s * (1.f / 256.f);
    float var = sq * (1.f / 256.f) - mean * mean;
    float rstd = rsqrtf(var + 1e-5f);
    float4 gv = ((const float4*)g)[l];
    float4 bv = ((const float4*)bsh)[l];
    bf16x4 o;
    o[0] = (bf16_t)((v.x - mean) * rstd * gv.x + bv.x);
    o[1] = (bf16_t)((v.y - mean) * rstd * gv.y + bv.y);
    o[2] = (bf16_t)((v.z - mean) * rstd * gv.z + bv.z);
    o[3] = (bf16_t)((v.w - mean) * rstd * gv.w + bv.w);
    *(bf16x4*)(out + (size_t)r * DIMC + l * 4) = o;
}

// ---------------- gemm_a: 128x256 tile, 512 thr, BK=32, 3-buffer (r12-validated) ------
// EPI: 0 = bias, bf16 | 1 = bias+gelu, bf16 | 2 = bias+resid, f32 |
//      3 = bias + scatter to xrow_of(r) + resid, f32
template <int EPI, int KT>
__global__ __launch_bounds__(512, 4) void gemm_a(const bf16_t* __restrict__ A,
                                                 const bf16_t* __restrict__ BT,
                                                 const float* __restrict__ bias,
                                                 int Nc,
                                                 bf16_t* __restrict__ outb,
                                                 float* __restrict__ outf,
                                                 const float* __restrict__ resid) {
    constexpr int NS = KT / 32;
    __shared__ __align__(16) char S[3][24576];
    int tid = threadIdx.x;
    int wv = tid >> 6, l = tid & 63;
    int wr = wv >> 2, wc = wv & 3;
    int nTilesN = Nc >> 8;
    int qn = gridDim.x >> 3;
    int lb = (blockIdx.x & 7) * qn + (blockIdx.x >> 3);
    int bm = lb / nTilesN, bn = lb - bm * nTilesN;
    size_t row0 = (size_t)bm * 128;
    int col0 = bn * 256;

    const char* Abase = (const char*)(A + row0 * KT);
    const char* Bbase = (const char*)(BT + (size_t)col0 * KT);
    const size_t ldb = (size_t)KT * 2;

    auto STAGE = [&](int b, int kk) {
        {
            int ci = tid;
            int sup = ci >> 3, slot = ci & 7;
            int us = slot ^ (sup & 7);
            int row = 2 * sup + (us >> 2), ch = us & 3;
            __builtin_amdgcn_global_load_lds(
                (const __attribute__((address_space(1))) void*)(Abase + (size_t)row * ldb + (size_t)kk * 2 + ch * 16),
                (__attribute__((address_space(3))) void*)(S[b] + ci * 16), 16, 0, 0);
        }
        #pragma unroll
        for (int it = 0; it < 2; ++it) {
            int ci = tid + it * 512;
            int sup = ci >> 3, slot = ci & 7;
            int us = slot ^ (sup & 7);
            int row = 2 * sup + (us >> 2), ch = us & 3;
            __builtin_amdgcn_global_load_lds(
                (const __attribute__((address_space(1))) void*)(Bbase + (size_t)row * ldb + (size_t)kk * 2 + ch * 16),
                (__attribute__((address_space(3))) void*)(S[b] + 8192 + ci * 16), 16, 0, 0);
        }
    };

    f32x4 acc[4][4] = {};
    const int lr = l & 15, g4 = l >> 4;

    STAGE(0, 0);
    STAGE(1, 32);

    #pragma unroll
    for (int s = 0; s < NS; ++s) {
        if (s + 1 < NS) { asm volatile("s_waitcnt vmcnt(3)" ::: "memory"); }
        else            { asm volatile("s_waitcnt vmcnt(0)" ::: "memory"); }
        __builtin_amdgcn_s_barrier();
        __builtin_amdgcn_sched_barrier(0);
        int buf = s % 3;
        if (s + 2 < NS) STAGE((s + 2) % 3, (s + 2) * 32);
        const char* Sb = S[buf];
        bf16x8 a[4], b[4];
        #pragma unroll
        for (int mt = 0; mt < 4; ++mt) {
            int r = wr * 64 + mt * 16 + lr;
            int sup = r >> 1;
            int us = ((r & 1) << 2) | g4;
            a[mt] = *(const bf16x8*)(Sb + sup * 128 + ((us ^ (sup & 7)) * 16));
        }
        #pragma unroll
        for (int nt = 0; nt < 4; ++nt) {
            int rc = wc * 64 + nt * 16 + lr;
            int sup = rc >> 1;
            int us = ((rc & 1) << 2) | g4;
            b[nt] = *(const bf16x8*)(Sb + 8192 + sup * 128 + ((us ^ (sup & 7)) * 16));
        }
        __builtin_amdgcn_s_setprio(1);
        #pragma unroll
        for (int mt = 0; mt < 4; ++mt)
            #pragma unroll
            for (int nt = 0; nt < 4; ++nt)
                acc[mt][nt] = __builtin_amdgcn_mfma_f32_16x16x32_bf16(a[mt], b[nt], acc[mt][nt], 0, 0, 0);
        __builtin_amdgcn_s_setprio(0);
        __builtin_amdgcn_sched_barrier(0);
    }

    #pragma unroll
    for (int m = 0; m < 4; ++m) {
        #pragma unroll
        for (int i = 0; i < 4; ++i) {
            int rr = (int)row0 + wr * 64 + m * 16 + g4 * 4 + i;
            size_t orow = (EPI == 3) ? (size_t)xrow_of(rr) * DIMC : (size_t)rr * Nc;
            #pragma unroll
            for (int n = 0; n < 4; ++n) {
                int cc = col0 + wc * 64 + n * 16 + lr;
                float v = acc[m][n][i] + bias[cc];
                if (EPI == 0) {
                    outb[(size_t)rr * Nc + cc] = (bf16_t)v;
                } else if (EPI == 1) {
                    float t3 = v + 0.044715f * v * v * v;
                    float e = __expf(-1.5957691216057308f * t3);
                    float gl = v * __builtin_amdgcn_rcpf(1.f + e);
                    outb[(size_t)rr * Nc + cc] = (bf16_t)gl;
                } else if (EPI == 2) {
                    size_t o = (size_t)rr * Nc + cc;
                    outf[o] = v + resid[o];
                } else {
                    size_t o = orow + cc;
                    outf[o] = v + resid[o];
                }
            }
        }
    }
}

// ---------------- gemm_b2: 256x256 tile, 1024 thr, BK=64, 2-buffer (r6 sync pattern) --
// LDS 2 x 64KB; row = 128B = 8 chunks, chunk c of row r at slot (c ^ (r&7))  [r6: 0 conflicts]
// 16 steps for K=1024: half the barrier crossings of BK=32.
template <int EPI, int KT>
__global__ __launch_bounds__(1024, 4) void gemm_b2(const bf16_t* __restrict__ A,
                                                   const bf16_t* __restrict__ BT,
                                                   const float* __restrict__ bias,
                                                   int Nc,
                                                   bf16_t* __restrict__ outb,
                                                   float* __restrict__ outf,
                                                   const float* __restrict__ resid) {
    constexpr int NS = KT / 64;
    __shared__ __align__(16) char S[2][65536];
    int tid = threadIdx.x;
    int wv = tid >> 6, l = tid & 63;
    int wr = wv >> 2, wc = wv & 3;
    int nTilesN = Nc >> 8;
    int qn = gridDim.x >> 3;
    int lb = (blockIdx.x & 7) * qn + (blockIdx.x >> 3);
    int bm = lb / nTilesN, bn = lb - bm * nTilesN;
    size_t row0 = (size_t)bm * 256;
    int col0 = bn * 256;

    const char* Abase = (const char*)(A + row0 * KT);
    const char* Bbase = (const char*)(BT + (size_t)col0 * KT);
    const size_t ldb = (size_t)KT * 2;

    // A: 256 rows x 128B = 2048 chunks (2/thread); B same (2/thread) -> 4 insts/thread
    auto STAGE = [&](int b, int kk) {
        #pragma unroll
        for (int it = 0; it < 2; ++it) {
            int ci = tid + it * 1024;
            int row = ci >> 3, ch = ci & 7;
            int sc = ch ^ (row & 7);
            __builtin_amdgcn_global_load_lds(
                (const __attribute__((address_space(1))) void*)(Abase + (size_t)row * ldb + (size_t)kk * 2 + sc * 16),
                (__attribute__((address_space(3))) void*)(S[b] + ci * 16), 16, 0, 0);
            __builtin_amdgcn_global_load_lds(
                (const __attribute__((address_space(1))) void*)(Bbase + (size_t)row * ldb + (size_t)kk * 2 + sc * 16),
                (__attribute__((address_space(3))) void*)(S[b] + 32768 + ci * 16), 16, 0, 0);
        }
    };

    f32x4 acc[4][4] = {};
    const int lr = l & 15, g4 = l >> 4;

    STAGE(0, 0);
    STAGE(1, 64);

    #pragma unroll
    for (int s = 0; s < NS; ++s) {
        if (s + 1 < NS) { asm volatile("s_waitcnt vmcnt(4)" ::: "memory"); }
        else            { asm volatile("s_waitcnt vmcnt(0)" ::: "memory"); }
        __builtin_amdgcn_s_barrier();
        __builtin_amdgcn_sched_barrier(0);
        int buf = s & 1;
        #pragma unroll
        for (int ks = 0; ks < 2; ++ks) {
            bf16x8 a[4], b[4];
            #pragma unroll
            for (int mt = 0; mt < 4; ++mt) {
                int r = wr * 64 + mt * 16 + lr;
                int c = (ks * 4 + g4) ^ (r & 7);
                a[mt] = *(const bf16x8*)(S[buf] + r * 128 + c * 16);
            }
            #pragma unroll
            for (int nt = 0; nt < 4; ++nt) {
                int rc = wc * 64 + nt * 16 + lr;
                int c = (ks * 4 + g4) ^ (rc & 7);
                b[nt] = *(const bf16x8*)(S[buf] + 32768 + rc * 128 + c * 16);
            }
            __builtin_amdgcn_s_setprio(1);
            #pragma unroll
            for (int mt = 0; mt < 4; ++mt)
                #pragma unroll
                for (int nt = 0; nt < 4; ++nt)
                    acc[mt][nt] = __builtin_amdgcn_mfma_f32_16x16x32_bf16(a[mt], b[nt], acc[mt][nt], 0, 0, 0);
            __builtin_amdgcn_s_setprio(0);
        }
        __builtin_amdgcn_s_barrier();
        __builtin_amdgcn_sched_barrier(0);
        if (s + 2 < NS) STAGE(buf, (s + 2) * 64);
    }

    #pragma unroll
    for (int m = 0; m < 4; ++m) {
        #pragma unroll
        for (int i = 0; i < 4; ++i) {
            int rr = (int)row0 + wr * 64 + m * 16 + g4 * 4 + i;
            #pragma unroll
            for (int n = 0; n < 4; ++n) {
                int cc = col0 + wc * 64 + n * 16 + lr;
                float v = acc[m][n][i] + bias[cc];
                if (EPI == 0) {
                    outb[(size_t)rr * Nc + cc] = (bf16_t)v;
                } else if (EPI == 1) {
                    float t3 = v + 0.044715f * v * v * v;
                    float e = __expf(-1.5957691216057308f * t3);
                    float gl = v * __builtin_amdgcn_rcpf(1.f + e);
                    outb[(size_t)rr * Nc + cc] = (bf16_t)gl;
                } else {
                    size_t o = (size_t)rr * Nc + cc;
                    outf[o] = v + resid[o];
                }
            }
        }
    }
}

// ---------------- MFMA windowed attention (Q/K direct-from-global fragments) ----------
__global__ __launch_bounds__(256) void attn_mfma(const bf16_t* __restrict__ qkv,
                                                 const float* __restrict__ bt,
                                                 bf16_t* __restrict__ out) {
    __shared__ __align__(16) char lds[4][12800];
    int wv = threadIdx.x >> 6, l = threadIdx.x & 63;
    int head = ((blockIdx.x & 1) << 2) | wv;
    int wi = blockIdx.x >> 1;
    char* W = lds[wv];                          // P region [0,8192)
    bf16_t* Vt = (bf16_t*)(W + 8192);           // [32][72]
    size_t rowbase = (size_t)wi * NTOK;
    const bf16_t* src = qkv + rowbase * 768 + head * HD;

    int w64 = wi & 63;
    int wh = w64 >> 3, ww = w64 & 7;
    bool lastH = (wh == 7), lastW = (ww == 7);
    bool masked = lastH || lastW;

    // ---- stage V transposed: Vt[d][m] (cols m>=49 zero-filled) ----
    #pragma unroll
    for (int it = 0; it < 4; ++it) {
        int t = l + it * 64;
        int m = t >> 2, dc = t & 3;
        if (m < NTOK) {
            bf16x8 vv = *(const bf16x8*)(src + (size_t)m * 768 + 512 + dc * 8);
            #pragma unroll
            for (int j = 0; j < 8; ++j) Vt[(dc * 8 + j) * 72 + m] = vv[j];
        } else {
            #pragma unroll
            for (int j = 0; j < 8; ++j) Vt[(dc * 8 + j) * 72 + m] = (bf16_t)0.f;
        }
    }

    int lr = l & 15, g4 = l >> 4;

    // ---- Q/K fragments straight from global (row = mt*16+lr, bytes g4*8..; 16B/lane) ----
    // rows >= 49 read into the adjacent allocated buffer (masked below) -- safe.
    bf16x8 a[4], b[4];
    #pragma unroll
    for (int mt = 0; mt < 4; ++mt) {
        int r = mt * 16 + lr;
        a[mt] = *(const bf16x8*)(src + (size_t)r * 768 + g4 * 8);
        b[mt] = *(const bf16x8*)(src + (size_t)r * 768 + 256 + g4 * 8);
    }
    f32x4 z = {0.f, 0.f, 0.f, 0.f};
    f32x4 S[4][4];
    #pragma unroll
    for (int mt = 0; mt < 4; ++mt)
        #pragma unroll
        for (int nt = 0; nt < 4; ++nt)
            S[mt][nt] = __builtin_amdgcn_mfma_f32_16x16x32_bf16(a[mt], b[nt], z, 0, 0, 0);

    int i2[4], j2[4], reg2[4];
    #pragma unroll
    for (int nt = 0; nt < 4; ++nt) {
        int cm = nt * 16 + lr;
        i2[nt] = (cm * 147) >> 10;
        j2[nt] = cm - i2[nt] * 7;
        int rh = lastH ? ((i2[nt] < 4) ? 1 : 2) : 0;
        int rw = lastW ? ((j2[nt] < 4) ? 1 : 2) : 0;
        reg2[nt] = rh * 3 + rw;
    }

    #pragma unroll
    for (int mt = 0; mt < 4; ++mt) {
        #pragma unroll
        for (int i = 0; i < 4; ++i) {
            int rn = mt * 16 + g4 * 4 + i;
            bool rowok = rn < NTOK;
            int i1 = (rn * 147) >> 10, j1 = rn - i1 * 7;
            int rh1 = lastH ? ((i1 < 4) ? 1 : 2) : 0;
            int rw1 = lastW ? ((j1 < 4) ? 1 : 2) : 0;
            int reg1 = rh1 * 3 + rw1;
            float sv[4];
            #pragma unroll
            for (int nt = 0; nt < 4; ++nt) {
                int cm = nt * 16 + lr;
                float sc;
                if (rowok && cm < NTOK) {
                    sc = S[mt][nt][i] * SCALE_QK;
                    sc += bt[((i1 - i2[nt] + 6) + 13 * (j1 - j2[nt] + 6)) * 8 + head];
                    if (masked && (reg1 != reg2[nt])) sc -= 100.f;
                } else {
                    sc = -1e30f;
                }
                sv[nt] = sc;
            }
            float mx = fmaxf(fmaxf(sv[0], sv[1]), fmaxf(sv[2], sv[3]));
            mx = fmaxf(mx, __shfl_xor(mx, 1));
            mx = fmaxf(mx, __shfl_xor(mx, 2));
            mx = fmaxf(mx, __shfl_xor(mx, 4));
            mx = fmaxf(mx, __shfl_xor(mx, 8));
            float e[4];
            float sum = 0.f;
            #pragma unroll
            for (int nt = 0; nt < 4; ++nt) { e[nt] = __expf(sv[nt] - mx); sum += e[nt]; }
            sum += __shfl_xor(sum, 1);
            sum += __shfl_xor(sum, 2);
            sum += __shfl_xor(sum, 4);
            sum += __shfl_xor(sum, 8);
            float inv = 1.f / sum;
            #pragma unroll
            for (int nt = 0; nt < 4; ++nt) {
                int cm = nt * 16 + lr;
                int pa = (rn * 128 + cm * 2) ^ ((rn & 7) << 4);
                *(bf16_t*)(W + pa) = (bf16_t)(e[nt] * inv);
            }
        }
    }

    f32x4 o[4][2] = {};
    #pragma unroll
    for (int ks = 0; ks < 2; ++ks) {
        bf16x8 pa[4], vb[2];
        #pragma unroll
        for (int mt = 0; mt < 4; ++mt) {
            int r = mt * 16 + lr;
            int ad = (r * 128 + ks * 64 + g4 * 16) ^ ((r & 7) << 4);
            pa[mt] = *(const bf16x8*)(W + ad);
        }
        #pragma unroll
        for (int dt = 0; dt < 2; ++dt) {
            int d = dt * 16 + lr;
            vb[dt] = *(const bf16x8*)((char*)Vt + d * 144 + ks * 64 + g4 * 16);
        }
        #pragma unroll
        for (int mt = 0; mt < 4; ++mt)
            #pragma unroll
            for (int dt = 0; dt < 2; ++dt)
                o[mt][dt] = __builtin_amdgcn_mfma_f32_16x16x32_bf16(pa[mt], vb[dt], o[mt][dt], 0, 0, 0);
    }

    #pragma unroll
    for (int mt = 0; mt < 4; ++mt) {
        #pragma unroll
        for (int i = 0; i < 4; ++i) {
            int n = mt * 16 + g4 * 4 + i;
            if (n < NTOK) {
                #pragma unroll
                for (int dt = 0; dt < 2; ++dt) {
                    out[(rowbase + n) * DIMC + head * HD + dt * 16 + lr] = (bf16_t)o[mt][dt][i];
                }
            }
        }
    }
}

extern "C" void kernel_launch(void* const* d_in, const int* in_sizes, int n_in,
                              void* d_out, int out_size, void* d_ws, size_t ws_size,
                              hipStream_t stream) {
    const float* x      = (const float*)d_in[0];
    const float* n1g    = (const float*)d_in[1];
    const float* n1b    = (const float*)d_in[2];
    const float* qkv_w  = (const float*)d_in[3];
    const float* qkv_b  = (const float*)d_in[4];
    const float* proj_w = (const float*)d_in[5];
    const float* proj_b = (const float*)d_in[6];
    const float* btab   = (const float*)d_in[7];
    const float* n2g    = (const float*)d_in[8];
    const float* n2b    = (const float*)d_in[9];
    const float* w1     = (const float*)d_in[10];
    const float* b1     = (const float*)d_in[11];
    const float* w2     = (const float*)d_in[12];
    const float* b2     = (const float*)d_in[13];

    char* ws = (char*)d_ws;
    bf16_t* win      = (bf16_t*)(ws);
    bf16_t* qkvbuf   = (bf16_t*)(ws + (size_t)T_TOK * 256 * 2);
    bf16_t* mlp1_buf = (bf16_t*)(ws);                       // aliases win+qkvbuf after proj
    bf16_t* h2       = (bf16_t*)(ws + (size_t)T_TOK * 2048);
    char* wtp        = ws + (size_t)T_TOK * 2048 + (size_t)T_TOK * 512;
    bf16_t* wt_qkv   = (bf16_t*)wtp;               // [768][256]
    bf16_t* wt_proj  = wt_qkv + 768 * 256;         // [256][256]
    bf16_t* wt_mlp1  = wt_proj + 256 * 256;        // [1024][256]
    bf16_t* wt_mlp2  = wt_mlp1 + 1024 * 256;       // [256][1024]
    float* xmid      = (float*)d_out;

    // all weight transposes in one launch (786432 elements / 256)
    transpose_all<<<3072, 256, 0, stream>>>(qkv_w, proj_w, w1, w2,
                                            wt_qkv, wt_proj, wt_mlp1, wt_mlp2);

    // LN1 + shift + window partition
    ln_kernel<1><<<T_TOK / 4, 256, 0, stream>>>(x, n1g, n1b, win);
    // QKV GEMM  [T,256] x [256,768]  (K=256 -> gemm_a)
    gemm_a<0, 256><<<(T_TOK / 128) * (768 / 256), 512, 0, stream>>>(win, wt_qkv, qkv_b, 768,
                                                                    qkvbuf, nullptr, nullptr);
    attn_mfma<<<2048 * 2, 256, 0, stream>>>(qkvbuf, btab, win);
    // proj GEMM + window reverse + unshift + residual -> xmid (= d_out)  (K=256 -> gemm_a)
    gemm_a<3, 256><<<(T_TOK / 128) * (256 / 256), 512, 0, stream>>>(win, wt_proj, proj_b, 256,
                                                                    nullptr, xmid, x);
    // LN2
    ln_kernel<0><<<T_TOK / 4, 256, 0, stream>>>(xmid, n2g, n2b, h2);
    // MLP1 + GELU  [T,256] x [256,1024]  (K=256 -> gemm_a)
    gemm_a<1, 256><<<(T_TOK / 128) * (1024 / 256), 512, 0, stream>>>(h2, wt_mlp1, b1, 1024,
                                                                     mlp1_buf, nullptr, nullptr);
    // MLP2 + residual  [T,1024] x [1024,256] -> d_out  (K=1024 -> gemm_b2, BK=64, 16 steps)
    gemm_b2<2, 1024><<<(T_TOK / 256) * (256 / 256), 1024, 0, stream>>>(mlp1_buf, wt_mlp2, b2, 256,
                                                                       nullptr, xmid, xmid);
}